// Round 2
// baseline (512.622 us; speedup 1.0000x reference)
//
#include <hip/hip_runtime.h>
#include <math.h>

#define BB 64
#define NN 4096
#define DD 256

// ---------------------------------------------------------------------------
// F-pass: for a chunk of rows, compute b[n] += m[n]*dot(s, x[n]) and
// accumulate per-wave online-softmax partials (M, Z, and optionally the
// exp-weighted partial sigma vector) for the NEXT iteration's weighted sum.
// Each wave owns rowsPerWave consecutive rows; lane i owns columns 4i..4i+3.
// FINAL: logits = b (final softmax), no sigma accumulation.
// ---------------------------------------------------------------------------
template<bool FINAL>
__global__ __launch_bounds__(256) void fpass_kernel(
    const float* __restrict__ x, const float* __restrict__ m,
    const float* __restrict__ s_buf, float* __restrict__ b_buf,
    float* __restrict__ part_sig, float* __restrict__ part_M,
    float* __restrict__ part_Z, int P, int rowsPerWave)
{
    const int lane = threadIdx.x & 63;
    const int wib  = threadIdx.x >> 6;        // wave in block (4 waves/block)
    const int bpb  = P >> 2;                  // blocks per batch
    const int batch = blockIdx.x / bpb;
    const int p = (blockIdx.x % bpb) * 4 + wib;
    const int n0 = p * rowsPerWave;

    const float4 s4 = reinterpret_cast<const float4*>(s_buf + batch * DD)[lane];
    const float4* __restrict__ xr =
        reinterpret_cast<const float4*>(x + ((size_t)batch * NN + n0) * DD) + lane;
    const float* __restrict__ mrow = m + (size_t)batch * NN + n0;
    float* __restrict__ brow = b_buf + (size_t)batch * NN + n0;

    float M = -INFINITY, Z = 0.f;
    float sx = 0.f, sy = 0.f, sz = 0.f, sw = 0.f;

    #pragma unroll 4
    for (int r = 0; r < rowsPerWave; ++r) {
        float4 xv = xr[(size_t)r * (DD / 4)];
        float mn = mrow[r];
        // dot(s, x_row): in-lane 4-wide, then 64-lane butterfly
        float dp = xv.x * s4.x + xv.y * s4.y + xv.z * s4.z + xv.w * s4.w;
        #pragma unroll
        for (int off = 32; off; off >>= 1) dp += __shfl_xor(dp, off, 64);
        float bn = brow[r] + mn * dp;         // b += m_n * (s . x_n)
        if (lane == 0) brow[r] = bn;
        float l = FINAL ? bn : mn * bn;       // final softmax uses b, not m*b
        // online softmax (wave-uniform branch: l identical across lanes)
        if (l > M) {
            float c = __expf(M - l);          // exp(-inf)=0 handles first row
            Z *= c;
            if (!FINAL) { sx *= c; sy *= c; sz *= c; sw *= c; }
            M = l;
        }
        float e = __expf(l - M);
        Z += e;
        if (!FINAL) {
            float wgt = e * mn;               // x_tilde = m * x
            sx += wgt * xv.x; sy += wgt * xv.y; sz += wgt * xv.z; sw += wgt * xv.w;
        }
    }
    if (!FINAL) {
        reinterpret_cast<float4*>(part_sig + ((size_t)batch * P + p) * DD)[lane] =
            make_float4(sx, sy, sz, sw);
    }
    if (lane == 0) {
        part_M[batch * P + p] = M;
        part_Z[batch * P + p] = Z;
    }
}

// ---------------------------------------------------------------------------
// Reduce: combine P wave-partials of one batch with max-rescaling.
// !FINAL: sigma = (sum_p c_p * part_sig_p)/Z, squash -> s_buf (and s_out).
// FINAL:  just write (Mg, Zg) for the final softmax.
// ---------------------------------------------------------------------------
template<bool FINAL>
__global__ __launch_bounds__(256) void reduce_kernel(
    const float* __restrict__ part_sig, const float* __restrict__ part_M,
    const float* __restrict__ part_Z, float* __restrict__ s_buf,
    float* __restrict__ s_out, float* __restrict__ MZf, int P)
{
    const int b = blockIdx.x;
    const int t = threadIdx.x;
    __shared__ float red[256];
    __shared__ float csh[128];

    float Mv = (t < P) ? part_M[b * P + t] : -INFINITY;
    red[t] = Mv;
    __syncthreads();
    for (int s = 128; s > 0; s >>= 1) {
        if (t < s) red[t] = fmaxf(red[t], red[t + s]);
        __syncthreads();
    }
    float Mg = red[0];
    __syncthreads();

    float zc = 0.f;
    if (t < P) {
        float c = expf(Mv - Mg);
        csh[t] = c;
        zc = part_Z[b * P + t] * c;
    }
    red[t] = zc;
    __syncthreads();
    for (int s = 128; s > 0; s >>= 1) {
        if (t < s) red[t] += red[t + s];
        __syncthreads();
    }
    float Zg = red[0];

    if (FINAL) {
        if (t == 0) { MZf[2 * b] = Mg; MZf[2 * b + 1] = Zg; }
        return;
    }
    __syncthreads();

    // thread t owns feature dim d = t
    float sig = 0.f;
    for (int p = 0; p < P; ++p)
        sig += csh[p] * part_sig[((size_t)b * P + p) * DD + t];
    sig /= Zg;

    red[t] = sig * sig;
    __syncthreads();
    for (int s = 128; s > 0; s >>= 1) {
        if (t < s) red[t] += red[t + s];
        __syncthreads();
    }
    float n2 = red[0];
    float nrm = sqrtf(n2);
    float scale = n2 / (1.f + n2) / (nrm + 1e-8f);   // squash
    float sv = scale * sig;
    s_buf[b * DD + t] = sv;
    if (s_out) s_out[b * DD + t] = sv;
}

// ---------------------------------------------------------------------------
// Final w = exp(b - M)/Z  (softmax over N, logits = b)
// ---------------------------------------------------------------------------
__global__ __launch_bounds__(256) void w_kernel(
    const float* __restrict__ b_buf, const float* __restrict__ MZf,
    float* __restrict__ w_out)
{
    int i = blockIdx.x * 256 + threadIdx.x;
    int b = i >> 12;   // N = 4096
    w_out[i] = __expf(b_buf[i] - MZf[2 * b]) / MZf[2 * b + 1];
}

extern "C" void kernel_launch(void* const* d_in, const int* in_sizes, int n_in,
                              void* d_out, int out_size, void* d_ws, size_t ws_size,
                              hipStream_t stream)
{
    const float* x = (const float*)d_in[0];
    const float* m = (const float*)d_in[1];
    float* out = (float*)d_out;                 // [B*N] w, then [B*D] s

    // pick partials-per-batch P to fit workspace
    int P = 128;
    auto needBytes = [](int Pv) -> size_t {
        return (size_t)(BB * NN + BB * DD + (size_t)BB * Pv * DD + BB * Pv * 2 + 2 * BB)
               * sizeof(float);
    };
    while (P > 8 && needBytes(P) > ws_size) P >>= 1;

    float* ws       = (float*)d_ws;
    float* b_buf    = ws;
    float* s_buf    = b_buf + BB * NN;
    float* part_sig = s_buf + BB * DD;
    float* part_M   = part_sig + (size_t)BB * P * DD;
    float* part_Z   = part_M + BB * P;
    float* MZf      = part_Z + BB * P;

    // b = 0 and s = 0 (pass 1 with s=0 reproduces the uniform first softmax)
    hipMemsetAsync(ws, 0, (size_t)(BB * NN + BB * DD) * sizeof(float), stream);

    const int rpw = NN / P;
    const int blocksF = BB * P / 4;
    float* s_final = out + BB * NN;

    for (int it = 0; it < 3; ++it) {
        fpass_kernel<false><<<blocksF, 256, 0, stream>>>(
            x, m, s_buf, b_buf, part_sig, part_M, part_Z, P, rpw);
        reduce_kernel<false><<<BB, 256, 0, stream>>>(
            part_sig, part_M, part_Z, s_buf, (it == 2) ? s_final : nullptr, MZf, P);
    }
    // final b-update + stats for softmax(b)
    fpass_kernel<true><<<blocksF, 256, 0, stream>>>(
        x, m, s_buf, b_buf, part_sig, part_M, part_Z, P, rpw);
    reduce_kernel<true><<<BB, 256, 0, stream>>>(
        part_sig, part_M, part_Z, s_buf, nullptr, MZf, P);
    w_kernel<<<BB * NN / 256, 256, 0, stream>>>(b_buf, MZf, out);
}